// Round 1
// baseline (409.994 us; speedup 1.0000x reference)
//
#include <hip/hip_runtime.h>

typedef __bf16 bf16x8 __attribute__((ext_vector_type(8)));
typedef float f32x4 __attribute__((ext_vector_type(4)));
typedef unsigned short u16;
typedef unsigned int u32;

#define MFMA16(a, b, c) __builtin_amdgcn_mfma_f32_16x16x32_bf16((a), (b), (c), 0, 0, 0)

__device__ __forceinline__ u16 f2b(float f) {
  u32 u = __float_as_uint(f);
  u += 0x7FFFu + ((u >> 16) & 1u);
  return (u16)(u >> 16);
}
__device__ __forceinline__ float b2f(u16 h) { return __uint_as_float(((u32)h) << 16); }

__device__ __forceinline__ void glds16(const void* g, void* l) {
  __builtin_amdgcn_global_load_lds((const __attribute__((address_space(1))) void*)g,
                                   (__attribute__((address_space(3))) void*)l, 16, 0, 0);
}

// ---------------- f32 -> bf16 conversion: x (8.4M) then WQ,WK,WV,WO (1M each) ----------------
__global__ __launch_bounds__(256) void cvt_k(const float* __restrict__ x,
                                             const float* __restrict__ wq,
                                             const float* __restrict__ wk,
                                             const float* __restrict__ wv,
                                             const float* __restrict__ wo,
                                             u16* __restrict__ dst) {
  size_t e = ((size_t)blockIdx.x * 256 + threadIdx.x) * 4;
  const float* src;
  size_t off;
  if (e < 8388608ull) {
    src = x; off = e;
  } else {
    size_t r = e - 8388608ull;
    u32 wi = (u32)(r >> 20);
    off = r & 1048575ull;
    src = (wi == 0) ? wq : (wi == 1) ? wk : (wi == 2) ? wv : wo;
  }
  float4 v = *(const float4*)(src + off);
  ushort4 o = make_ushort4(f2b(v.x), f2b(v.y), f2b(v.z), f2b(v.w));
  *(ushort4*)(dst + e) = o;
}

// ---------------- RoPE cos/sin table: tab[(b*S+s)*32 + j] = (cos, sin) ----------------
__global__ __launch_bounds__(256) void rope_tab_k(const int* __restrict__ pos,
                                                  float2* __restrict__ tab) {
  int i = blockIdx.x * 256 + threadIdx.x;  // 262144 total
  int row = i >> 5, j = i & 31;
  float p = (float)pos[row];
  float inv = exp2f((float)j * -0.41524101186092029f);  // 10000^(-j/32)
  float s, c;
  sincosf(p * inv, &s, &c);
  tab[i] = make_float2(c, s);
}

// ---------------- QKV projection GEMM: C[s,e] = sum_d X[s,d] * W[e,d] ----------------
// 128x128 tile, BK=32, 4 waves (2x2 of 64x64), global_load_lds staging.
__global__ __launch_bounds__(256) void gemm_qkv_k(const u16* __restrict__ Xb,
                                                  const u16* __restrict__ Wq,
                                                  const u16* __restrict__ Wk,
                                                  const u16* __restrict__ Wv,
                                                  u16* __restrict__ Qp,
                                                  u16* __restrict__ Kp,
                                                  u16* __restrict__ Vt) {
  __shared__ u16 As[128 * 32];
  __shared__ u16 Bs[128 * 32];
  const int z = blockIdx.z;
  const u16* W = (z == 0) ? Wq : (z == 1) ? Wk : Wv;
  const int mt = blockIdx.y, nt = blockIdx.x;
  const int tid = threadIdx.x, wave = tid >> 6, lane = tid & 63;
  const int wr = (wave >> 1) * 64, wc = (wave & 1) * 64;
  const int lr = lane & 15, lg = lane >> 4;

  const size_t arow = (size_t)(mt * 128 + wave * 32 + (lane >> 2)) * 1024 + (lane & 3) * 8;
  const size_t brow = (size_t)(nt * 128 + wave * 32 + (lane >> 2)) * 1024 + (lane & 3) * 8;
  u16* Ad0 = &As[(wave * 32) * 32];
  u16* Ad1 = &As[(wave * 32 + 16) * 32];
  u16* Bd0 = &Bs[(wave * 32) * 32];
  u16* Bd1 = &Bs[(wave * 32 + 16) * 32];

  f32x4 acc[4][4];
#pragma unroll
  for (int i = 0; i < 4; ++i)
#pragma unroll
    for (int j = 0; j < 4; ++j) acc[i][j] = (f32x4){0.f, 0.f, 0.f, 0.f};

  for (int kt = 0; kt < 1024; kt += 32) {
    glds16(Xb + arow + kt, Ad0);
    glds16(Xb + arow + kt + 16 * 1024, Ad1);
    glds16(W + brow + kt, Bd0);
    glds16(W + brow + kt + 16 * 1024, Bd1);
    __syncthreads();
    bf16x8 af[4], bfr[4];
#pragma unroll
    for (int mi = 0; mi < 4; ++mi)
      af[mi] = *(const bf16x8*)&As[(wr + mi * 16 + lr) * 32 + lg * 8];
#pragma unroll
    for (int ni = 0; ni < 4; ++ni)
      bfr[ni] = *(const bf16x8*)&Bs[(wc + ni * 16 + lr) * 32 + lg * 8];
#pragma unroll
    for (int mi = 0; mi < 4; ++mi)
#pragma unroll
      for (int ni = 0; ni < 4; ++ni)
        acc[mi][ni] = MFMA16(af[mi], bfr[ni], acc[mi][ni]);
    __syncthreads();
  }

  if (z < 2) {
    u16* out = (z == 0) ? Qp : Kp;
#pragma unroll
    for (int mi = 0; mi < 4; ++mi)
#pragma unroll
      for (int ni = 0; ni < 4; ++ni) {
        int row0 = mt * 128 + wr + mi * 16 + lg * 4;
        int col = nt * 128 + wc + ni * 16 + lr;
#pragma unroll
        for (int r = 0; r < 4; ++r)
          out[(size_t)(row0 + r) * 1024 + col] = f2b(acc[mi][ni][r]);
      }
  } else {
    // V stored transposed: Vt[((b*1024 + e) * 2048) + s]
#pragma unroll
    for (int mi = 0; mi < 4; ++mi)
#pragma unroll
      for (int ni = 0; ni < 4; ++ni) {
        int row0 = mt * 128 + wr + mi * 16 + lg * 4;  // global s-row (multiple of 4)
        int e = nt * 128 + wc + ni * 16 + lr;
        int b = row0 >> 11, s = row0 & 2047;
        ushort4 pk = make_ushort4(f2b(acc[mi][ni][0]), f2b(acc[mi][ni][1]),
                                  f2b(acc[mi][ni][2]), f2b(acc[mi][ni][3]));
        *(ushort4*)&Vt[((size_t)(b * 1024 + e)) * 2048 + s] = pk;
      }
  }
}

// ---------------- RoPE applied in-place to Qp (scaled by 0.125) and Kp ----------------
__global__ __launch_bounds__(256) void rope_k(u16* __restrict__ Qp, u16* __restrict__ Kp,
                                              const float2* __restrict__ tab) {
  u32 idx = blockIdx.x * 256 + threadIdx.x;  // 8388608 total
  u32 pairidx = idx & 511u;
  u32 row = (idx >> 9) & 8191u;
  u32 which = idx >> 22;
  u32 h = pairidx >> 5, j = pairidx & 31u;
  u32 col = h * 64 + j * 2;
  u16* buf = which ? Kp : Qp;
  float2 cs = tab[row * 32 + j];
  u32* p = (u32*)(buf + (size_t)row * 1024 + col);
  u32 v = *p;
  float e = b2f((u16)v), o = b2f((u16)(v >> 16));
  float scl = which ? 1.0f : 0.125f;  // fold 1/sqrt(64) into Q
  float re = (e * cs.x - o * cs.y) * scl;
  float ro = (e * cs.y + o * cs.x) * scl;
  *p = ((u32)f2b(ro) << 16) | (u32)f2b(re);
}

// ---------------- causal flash attention ----------------
// grid (32 q-tiles, 64 bh); 4 waves; 16 q-rows/wave, KVBLK=64.
__global__ __launch_bounds__(256) void fattn_k(const u16* __restrict__ Qp,
                                               const u16* __restrict__ Kp,
                                               const u16* __restrict__ Vt,
                                               u16* __restrict__ Ao) {
  __shared__ u16 Ks[64 * 64];      // [kv][d]
  __shared__ u16 Vs[64 * 64];      // [d][kv]  (from transposed V)
  __shared__ u16 Ps[4][16 * 64];   // per-wave P tile [q][kv]
  const int qt = (int)gridDim.x - 1 - (int)blockIdx.x;  // long blocks first
  const int bh = blockIdx.y;
  const int b = bh >> 4, h = bh & 15;
  const int tid = threadIdx.x, wave = tid >> 6, lane = tid & 63;
  const int lr = lane & 15, lg = lane >> 4;
  const int q0 = qt * 64 + wave * 16;

  const u16* qb = Qp + ((size_t)(b * 2048 + q0 + lr)) * 1024 + h * 64 + lg * 8;
  bf16x8 qf0 = *(const bf16x8*)qb;
  bf16x8 qf1 = *(const bf16x8*)(qb + 32);

  float m[4], l[4];
  f32x4 oacc[4];
#pragma unroll
  for (int r = 0; r < 4; ++r) { m[r] = -1e30f; l[r] = 0.f; }
#pragma unroll
  for (int d4 = 0; d4 < 4; ++d4) oacc[d4] = (f32x4){0.f, 0.f, 0.f, 0.f};

  const int trow = wave * 16 + (lane >> 3);
  const u16* ksrc = Kp + ((size_t)(b * 2048 + trow)) * 1024 + h * 64 + (lane & 7) * 8;
  const u16* vsrc = Vt + ((size_t)(b * 1024 + h * 64 + trow)) * 2048 + (lane & 7) * 8;

  for (int kt = 0; kt <= qt; ++kt) {
    __syncthreads();  // protect LDS reuse across iterations
    glds16(ksrc + (size_t)(kt * 64) * 1024, &Ks[(wave * 16) * 64]);
    glds16(ksrc + (size_t)(kt * 64 + 8) * 1024, &Ks[(wave * 16 + 8) * 64]);
    glds16(vsrc + kt * 64, &Vs[(wave * 16) * 64]);
    glds16(vsrc + 8 * 2048 + kt * 64, &Vs[(wave * 16 + 8) * 64]);
    __syncthreads();

    // QK^T: S[q][kv], 4 kv-subtiles x 2 k-chunks
    f32x4 sc4[4];
#pragma unroll
    for (int ks = 0; ks < 4; ++ks) {
      bf16x8 kf0 = *(const bf16x8*)&Ks[(ks * 16 + lr) * 64 + lg * 8];
      bf16x8 kf1 = *(const bf16x8*)&Ks[(ks * 16 + lr) * 64 + 32 + lg * 8];
      f32x4 s = (f32x4){0.f, 0.f, 0.f, 0.f};
      s = MFMA16(qf0, kf0, s);
      s = MFMA16(qf1, kf1, s);
      sc4[ks] = s;
    }
    if (kt == qt) {  // causal mask, diagonal tile only
#pragma unroll
      for (int ks = 0; ks < 4; ++ks)
#pragma unroll
        for (int r = 0; r < 4; ++r) {
          int q = q0 + lg * 4 + r;
          int kv = kt * 64 + ks * 16 + lr;
          if (kv > q) sc4[ks][r] = -__builtin_inff();
        }
    }
    // online softmax (row reductions across 16-lane groups)
    float pm[4], rs[4], corr[4];
#pragma unroll
    for (int r = 0; r < 4; ++r)
      pm[r] = fmaxf(fmaxf(sc4[0][r], sc4[1][r]), fmaxf(sc4[2][r], sc4[3][r]));
#pragma unroll
    for (int off = 1; off < 16; off <<= 1)
#pragma unroll
      for (int r = 0; r < 4; ++r) pm[r] = fmaxf(pm[r], __shfl_xor(pm[r], off, 16));
#pragma unroll
    for (int r = 0; r < 4; ++r) {
      float mn = fmaxf(m[r], pm[r]);
      corr[r] = __expf(m[r] - mn);
      m[r] = mn;
      float ps = 0.f;
#pragma unroll
      for (int ks = 0; ks < 4; ++ks) {
        float p = __expf(sc4[ks][r] - mn);
        sc4[ks][r] = p;
        ps += p;
      }
      rs[r] = ps;
    }
#pragma unroll
    for (int off = 1; off < 16; off <<= 1)
#pragma unroll
      for (int r = 0; r < 4; ++r) rs[r] += __shfl_xor(rs[r], off, 16);
#pragma unroll
    for (int r = 0; r < 4; ++r) l[r] = l[r] * corr[r] + rs[r];
#pragma unroll
    for (int d4 = 0; d4 < 4; ++d4)
#pragma unroll
      for (int r = 0; r < 4; ++r) oacc[d4][r] *= corr[r];
    // P -> bf16 -> LDS (re-layout for PV A-operand)
#pragma unroll
    for (int ks = 0; ks < 4; ++ks)
#pragma unroll
      for (int r = 0; r < 4; ++r)
        Ps[wave][(lg * 4 + r) * 64 + ks * 16 + lr] = f2b(sc4[ks][r]);
    __syncthreads();
    bf16x8 pf0 = *(const bf16x8*)&Ps[wave][lr * 64 + lg * 8];
    bf16x8 pf1 = *(const bf16x8*)&Ps[wave][lr * 64 + 32 + lg * 8];
#pragma unroll
    for (int d4 = 0; d4 < 4; ++d4) {
      bf16x8 vf0 = *(const bf16x8*)&Vs[(d4 * 16 + lr) * 64 + lg * 8];
      bf16x8 vf1 = *(const bf16x8*)&Vs[(d4 * 16 + lr) * 64 + 32 + lg * 8];
      oacc[d4] = MFMA16(pf0, vf0, oacc[d4]);
      oacc[d4] = MFMA16(pf1, vf1, oacc[d4]);
    }
  }
#pragma unroll
  for (int r = 0; r < 4; ++r) {
    float inv = 1.f / l[r];
    int q = q0 + lg * 4 + r;
    u16* orow = Ao + ((size_t)(b * 2048 + q)) * 1024 + h * 64 + lr;
#pragma unroll
    for (int d4 = 0; d4 < 4; ++d4) orow[d4 * 16] = f2b(oacc[d4][r] * inv);
  }
}

// ---------------- output projection: Out[s,o] = sum_e Ao[s,e] * WO[o,e] (f32 out) ----------------
__global__ __launch_bounds__(256) void gemm_wo_k(const u16* __restrict__ Ab,
                                                 const u16* __restrict__ Wo,
                                                 float* __restrict__ Out) {
  __shared__ u16 As[128 * 32];
  __shared__ u16 Bs[128 * 32];
  const int mt = blockIdx.y, nt = blockIdx.x;
  const int tid = threadIdx.x, wave = tid >> 6, lane = tid & 63;
  const int wr = (wave >> 1) * 64, wc = (wave & 1) * 64;
  const int lr = lane & 15, lg = lane >> 4;
  const size_t arow = (size_t)(mt * 128 + wave * 32 + (lane >> 2)) * 1024 + (lane & 3) * 8;
  const size_t brow = (size_t)(nt * 128 + wave * 32 + (lane >> 2)) * 1024 + (lane & 3) * 8;
  u16* Ad0 = &As[(wave * 32) * 32];
  u16* Ad1 = &As[(wave * 32 + 16) * 32];
  u16* Bd0 = &Bs[(wave * 32) * 32];
  u16* Bd1 = &Bs[(wave * 32 + 16) * 32];

  f32x4 acc[4][4];
#pragma unroll
  for (int i = 0; i < 4; ++i)
#pragma unroll
    for (int j = 0; j < 4; ++j) acc[i][j] = (f32x4){0.f, 0.f, 0.f, 0.f};

  for (int kt = 0; kt < 1024; kt += 32) {
    glds16(Ab + arow + kt, Ad0);
    glds16(Ab + arow + kt + 16 * 1024, Ad1);
    glds16(Wo + brow + kt, Bd0);
    glds16(Wo + brow + kt + 16 * 1024, Bd1);
    __syncthreads();
    bf16x8 af[4], bfr[4];
#pragma unroll
    for (int mi = 0; mi < 4; ++mi)
      af[mi] = *(const bf16x8*)&As[(wr + mi * 16 + lr) * 32 + lg * 8];
#pragma unroll
    for (int ni = 0; ni < 4; ++ni)
      bfr[ni] = *(const bf16x8*)&Bs[(wc + ni * 16 + lr) * 32 + lg * 8];
#pragma unroll
    for (int mi = 0; mi < 4; ++mi)
#pragma unroll
      for (int ni = 0; ni < 4; ++ni)
        acc[mi][ni] = MFMA16(af[mi], bfr[ni], acc[mi][ni]);
    __syncthreads();
  }
#pragma unroll
  for (int mi = 0; mi < 4; ++mi)
#pragma unroll
    for (int ni = 0; ni < 4; ++ni) {
      int row0 = mt * 128 + wr + mi * 16 + lg * 4;
      int col = nt * 128 + wc + ni * 16 + lr;
#pragma unroll
      for (int r = 0; r < 4; ++r)
        Out[(size_t)(row0 + r) * 1024 + col] = acc[mi][ni][r];
    }
}

extern "C" void kernel_launch(void* const* d_in, const int* in_sizes, int n_in,
                              void* d_out, int out_size, void* d_ws, size_t ws_size,
                              hipStream_t stream) {
  const float* x = (const float*)d_in[0];
  const int* pos = (const int*)d_in[1];
  const float* wq = (const float*)d_in[2];
  const float* wk = (const float*)d_in[3];
  const float* wv = (const float*)d_in[4];
  const float* wo = (const float*)d_in[5];

  char* ws = (char*)d_ws;
  u16* xb = (u16*)ws;                          // 8388608 elems = 16 MB
  u16* wqb = xb + 8388608;                     // 1M elems each
  u16* wkb = wqb + 1048576;
  u16* wvb = wkb + 1048576;
  u16* wob = wvb + 1048576;
  float2* tab = (float2*)(ws + 25165824);      // 2 MB
  u16* Qp = (u16*)(ws + 27262976);             // 16 MB
  u16* Kp = (u16*)(ws + 27262976 + 16777216);  // 16 MB
  u16* Vt = (u16*)(ws + 27262976 + 2 * 16777216);  // 16 MB (transposed V)
  u16* Ao = (u16*)(ws + 27262976 + 3 * 16777216);  // 16 MB

  hipLaunchKernelGGL(cvt_k, dim3(12288), dim3(256), 0, stream, x, wq, wk, wv, wo, xb);
  hipLaunchKernelGGL(rope_tab_k, dim3(1024), dim3(256), 0, stream, pos, tab);
  hipLaunchKernelGGL(gemm_qkv_k, dim3(8, 64, 3), dim3(256), 0, stream, xb, wqb, wkb, wvb,
                     Qp, Kp, Vt);
  hipLaunchKernelGGL(rope_k, dim3(32768), dim3(256), 0, stream, Qp, Kp, tab);
  hipLaunchKernelGGL(fattn_k, dim3(32, 64), dim3(256), 0, stream, Qp, Kp, Vt, Ao);
  hipLaunchKernelGGL(gemm_wo_k, dim3(8, 64), dim3(256), 0, stream, Ao, wob, (float*)d_out);
}

// Round 2
// 224.880 us; speedup vs baseline: 1.8232x; 1.8232x over previous
//
#include <hip/hip_runtime.h>

typedef __bf16 bf16x8 __attribute__((ext_vector_type(8)));
typedef float f32x4 __attribute__((ext_vector_type(4)));
typedef unsigned short u16;
typedef unsigned int u32;

#define MFMA16(a, b, c) __builtin_amdgcn_mfma_f32_16x16x32_bf16((a), (b), (c), 0, 0, 0)

__device__ __forceinline__ u16 f2b(float f) {
  u32 u = __float_as_uint(f);
  u += 0x7FFFu + ((u >> 16) & 1u);
  return (u16)(u >> 16);
}
__device__ __forceinline__ float b2f(u16 h) { return __uint_as_float(((u32)h) << 16); }

__device__ __forceinline__ void glds16(const void* g, void* l) {
  __builtin_amdgcn_global_load_lds((const __attribute__((address_space(1))) void*)g,
                                   (__attribute__((address_space(3))) void*)l, 16, 0, 0);
}

// ---------------- f32 -> bf16 conversion: x (8.4M) then WQ,WK,WV,WO (1M each) ----------------
__global__ __launch_bounds__(256) void cvt_k(const float* __restrict__ x,
                                             const float* __restrict__ wq,
                                             const float* __restrict__ wk,
                                             const float* __restrict__ wv,
                                             const float* __restrict__ wo,
                                             u16* __restrict__ dst) {
  size_t e = ((size_t)blockIdx.x * 256 + threadIdx.x) * 4;
  const float* src;
  size_t off;
  if (e < 8388608ull) {
    src = x; off = e;
  } else {
    size_t r = e - 8388608ull;
    u32 wi = (u32)(r >> 20);
    off = r & 1048575ull;
    src = (wi == 0) ? wq : (wi == 1) ? wk : (wi == 2) ? wv : wo;
  }
  float4 v = *(const float4*)(src + off);
  ushort4 o = make_ushort4(f2b(v.x), f2b(v.y), f2b(v.z), f2b(v.w));
  *(ushort4*)(dst + e) = o;
}

// ---------------- RoPE cos/sin table ----------------
__global__ __launch_bounds__(256) void rope_tab_k(const int* __restrict__ pos,
                                                  float2* __restrict__ tab) {
  int i = blockIdx.x * 256 + threadIdx.x;  // 262144 total
  int row = i >> 5, j = i & 31;
  float p = (float)pos[row];
  float inv = exp2f((float)j * -0.41524101186092029f);  // 10000^(-j/32)
  float s, c;
  sincosf(p * inv, &s, &c);
  tab[i] = make_float2(c, s);
}

// ---------------- QKV projection GEMM ----------------
__global__ __launch_bounds__(256) void gemm_qkv_k(const u16* __restrict__ Xb,
                                                  const u16* __restrict__ Wq,
                                                  const u16* __restrict__ Wk,
                                                  const u16* __restrict__ Wv,
                                                  u16* __restrict__ Qp,
                                                  u16* __restrict__ Kp,
                                                  u16* __restrict__ Vt) {
  __shared__ u16 As[128 * 32];
  __shared__ u16 Bs[128 * 32];
  const int z = blockIdx.z;
  const u16* W = (z == 0) ? Wq : (z == 1) ? Wk : Wv;
  const int mt = blockIdx.y, nt = blockIdx.x;
  const int tid = threadIdx.x, wave = tid >> 6, lane = tid & 63;
  const int wr = (wave >> 1) * 64, wc = (wave & 1) * 64;
  const int lr = lane & 15, lg = lane >> 4;

  const size_t arow = (size_t)(mt * 128 + wave * 32 + (lane >> 2)) * 1024 + (lane & 3) * 8;
  const size_t brow = (size_t)(nt * 128 + wave * 32 + (lane >> 2)) * 1024 + (lane & 3) * 8;
  u16* Ad0 = &As[(wave * 32) * 32];
  u16* Ad1 = &As[(wave * 32 + 16) * 32];
  u16* Bd0 = &Bs[(wave * 32) * 32];
  u16* Bd1 = &Bs[(wave * 32 + 16) * 32];

  f32x4 acc[4][4];
#pragma unroll
  for (int i = 0; i < 4; ++i)
#pragma unroll
    for (int j = 0; j < 4; ++j) acc[i][j] = (f32x4){0.f, 0.f, 0.f, 0.f};

  for (int kt = 0; kt < 1024; kt += 32) {
    glds16(Xb + arow + kt, Ad0);
    glds16(Xb + arow + kt + 16 * 1024, Ad1);
    glds16(W + brow + kt, Bd0);
    glds16(W + brow + kt + 16 * 1024, Bd1);
    __syncthreads();
    bf16x8 af[4], bfr[4];
#pragma unroll
    for (int mi = 0; mi < 4; ++mi)
      af[mi] = *(const bf16x8*)&As[(wr + mi * 16 + lr) * 32 + lg * 8];
#pragma unroll
    for (int ni = 0; ni < 4; ++ni)
      bfr[ni] = *(const bf16x8*)&Bs[(wc + ni * 16 + lr) * 32 + lg * 8];
#pragma unroll
    for (int mi = 0; mi < 4; ++mi)
#pragma unroll
      for (int ni = 0; ni < 4; ++ni)
        acc[mi][ni] = MFMA16(af[mi], bfr[ni], acc[mi][ni]);
    __syncthreads();
  }

  if (z < 2) {
    u16* out = (z == 0) ? Qp : Kp;
#pragma unroll
    for (int mi = 0; mi < 4; ++mi)
#pragma unroll
      for (int ni = 0; ni < 4; ++ni) {
        int row0 = mt * 128 + wr + mi * 16 + lg * 4;
        int col = nt * 128 + wc + ni * 16 + lr;
#pragma unroll
        for (int r = 0; r < 4; ++r)
          out[(size_t)(row0 + r) * 1024 + col] = f2b(acc[mi][ni][r]);
      }
  } else {
#pragma unroll
    for (int mi = 0; mi < 4; ++mi)
#pragma unroll
      for (int ni = 0; ni < 4; ++ni) {
        int row0 = mt * 128 + wr + mi * 16 + lg * 4;
        int e = nt * 128 + wc + ni * 16 + lr;
        int b = row0 >> 11, s = row0 & 2047;
        ushort4 pk = make_ushort4(f2b(acc[mi][ni][0]), f2b(acc[mi][ni][1]),
                                  f2b(acc[mi][ni][2]), f2b(acc[mi][ni][3]));
        *(ushort4*)&Vt[((size_t)(b * 1024 + e)) * 2048 + s] = pk;
      }
  }
}

// ---------------- RoPE in-place (Q scaled by 0.125) ----------------
__global__ __launch_bounds__(256) void rope_k(u16* __restrict__ Qp, u16* __restrict__ Kp,
                                              const float2* __restrict__ tab) {
  u32 idx = blockIdx.x * 256 + threadIdx.x;  // 8388608 total
  u32 pairidx = idx & 511u;
  u32 row = (idx >> 9) & 8191u;
  u32 which = idx >> 22;
  u32 h = pairidx >> 5, j = pairidx & 31u;
  u32 col = h * 64 + j * 2;
  u16* buf = which ? Kp : Qp;
  float2 cs = tab[row * 32 + j];
  u32* p = (u32*)(buf + (size_t)row * 1024 + col);
  u32 v = *p;
  float e = b2f((u16)v), o = b2f((u16)(v >> 16));
  float scl = which ? 1.0f : 0.125f;
  float re = (e * cs.x - o * cs.y) * scl;
  float ro = (e * cs.y + o * cs.x) * scl;
  *p = ((u32)f2b(ro) << 16) | (u32)f2b(re);
}

// ---------------- causal flash attention (swizzled, swapped-QK^T, 128 q/block) ----------------
// 1024 blocks linear. xcd = blk&7 owns bh in [8*xcd, 8*xcd+8) (K/V set = 4MB = one L2).
// 4 waves x 32 q-rows. KVBLK=64. LDS tiles XOR-swizzled: chunk ^= (row&7).
__global__ __launch_bounds__(256) void fattn_k(const u16* __restrict__ Qp,
                                               const u16* __restrict__ Kp,
                                               const u16* __restrict__ Vt,
                                               u16* __restrict__ Ao) {
  __shared__ u16 Ks[64 * 64];       // [kv][d], swizzled
  __shared__ u16 Vs[64 * 64];       // [d][kv], swizzled
  __shared__ u16 Ps[4][32 * 64];    // per-wave [q][kv], swizzled
  const int blk = blockIdx.x;
  const int g = blk & 7, j = blk >> 3;
  const int bh = g * 8 + (j & 7);
  const int qt = 15 - (j >> 3);     // long blocks first
  const int b = bh >> 4, h = bh & 15;
  const int tid = threadIdx.x, wave = tid >> 6, lane = tid & 63;
  const int lr = lane & 15, lg = lane >> 4;
  const int q0w = qt * 128 + wave * 32;

  // Q fragments (B-operand rows = q), scale 0.125 already folded in
  bf16x8 qf[2][2];
#pragma unroll
  for (int qh = 0; qh < 2; ++qh) {
    const u16* qb = Qp + ((size_t)(b * 2048 + q0w + qh * 16 + lr)) * 1024 + h * 64 + lg * 8;
    qf[qh][0] = *(const bf16x8*)qb;
    qf[qh][1] = *(const bf16x8*)(qb + 32);
  }

  float m[2], l[2];
  f32x4 oacc[2][4];
#pragma unroll
  for (int qh = 0; qh < 2; ++qh) {
    m[qh] = -1e30f; l[qh] = 0.f;
#pragma unroll
    for (int d4 = 0; d4 < 4; ++d4) oacc[qh][d4] = (f32x4){0.f, 0.f, 0.f, 0.f};
  }

  // staging: wave w stages rows [16w,16w+16); source chunk pre-swizzled by row&7
  const int srow = lane >> 3;                  // 0..7
  const int schunk = (lane & 7) ^ srow;        // XOR swizzle
  const u16* kbase = Kp + ((size_t)(b * 2048 + 16 * wave + srow)) * 1024 + h * 64 + schunk * 8;
  const u16* vbase = Vt + ((size_t)(b * 1024 + h * 64 + 16 * wave + srow)) * 2048 + schunk * 8;
  u16* kdst0 = &Ks[(16 * wave) * 64];
  u16* kdst1 = &Ks[(16 * wave + 8) * 64];
  u16* vdst0 = &Vs[(16 * wave) * 64];
  u16* vdst1 = &Vs[(16 * wave + 8) * 64];
  char* psbase = (char*)&Ps[wave][0];

  const int ktmax = 2 * qt + 1;
  const int ktmask = q0w >> 6;                 // first kt needing causal mask
  const int ktneed = 2 * qt + (wave >> 1);     // last kt this wave needs

  for (int kt = 0; kt <= ktmax; ++kt) {
    __syncthreads();
    glds16(kbase + (size_t)kt * 65536, kdst0);
    glds16(kbase + (size_t)kt * 65536 + 8192, kdst1);
    glds16(vbase + kt * 64, vdst0);
    glds16(vbase + kt * 64 + 16384, vdst1);
    __syncthreads();
    if (kt > ktneed) continue;

    // QK^T swapped: S^T[kv][q]; lane holds kv = ks*16+lg*4+r for q = q0w+qh*16+lr
    f32x4 sc[2][4];
#pragma unroll
    for (int ks = 0; ks < 4; ++ks) {
      const int krow = ks * 16 + lr;
      const int sw = lr & 7;
      bf16x8 kf0 = *(const bf16x8*)&Ks[krow * 64 + ((lg ^ sw) * 8)];
      bf16x8 kf1 = *(const bf16x8*)&Ks[krow * 64 + (((lg + 4) ^ sw) * 8)];
#pragma unroll
      for (int qh = 0; qh < 2; ++qh) {
        f32x4 s = (f32x4){0.f, 0.f, 0.f, 0.f};
        s = MFMA16(kf0, qf[qh][0], s);
        s = MFMA16(kf1, qf[qh][1], s);
        sc[qh][ks] = s;
      }
    }
    if (kt >= ktmask) {  // causal mask
#pragma unroll
      for (int qh = 0; qh < 2; ++qh) {
        int q = q0w + qh * 16 + lr;
#pragma unroll
        for (int ks = 0; ks < 4; ++ks)
#pragma unroll
          for (int r = 0; r < 4; ++r) {
            int kv = kt * 64 + ks * 16 + lg * 4 + r;
            if (kv > q) sc[qh][ks][r] = -__builtin_inff();
          }
      }
    }

    // online softmax: full row is in-register (16 vals) + 2 cross-lane hops
#pragma unroll
    for (int qh = 0; qh < 2; ++qh) {
      float pm = sc[qh][0][0];
#pragma unroll
      for (int ks = 0; ks < 4; ++ks)
#pragma unroll
        for (int r = 0; r < 4; ++r) pm = fmaxf(pm, sc[qh][ks][r]);
      pm = fmaxf(pm, __shfl_xor(pm, 16));
      pm = fmaxf(pm, __shfl_xor(pm, 32));
      float mn = fmaxf(m[qh], pm);
      float corr = __expf(m[qh] - mn);
      m[qh] = mn;
      float rs = 0.f;
#pragma unroll
      for (int ks = 0; ks < 4; ++ks)
#pragma unroll
        for (int r = 0; r < 4; ++r) {
          float p = __expf(sc[qh][ks][r] - mn);
          sc[qh][ks][r] = p;
          rs += p;
        }
      rs += __shfl_xor(rs, 16);
      rs += __shfl_xor(rs, 32);
      l[qh] = l[qh] * corr + rs;
      float cb[4];
#pragma unroll
      for (int r = 0; r < 4; ++r) cb[r] = __shfl(corr, (lane & 48) | (lg * 4 + r));
#pragma unroll
      for (int d4 = 0; d4 < 4; ++d4)
#pragma unroll
        for (int r = 0; r < 4; ++r) oacc[qh][d4][r] *= cb[r];
    }

    // P -> bf16 -> swizzled per-wave LDS tile [q][kv]
#pragma unroll
    for (int qh = 0; qh < 2; ++qh) {
      const int row = qh * 16 + lr;
      const int sw = lr & 7;
#pragma unroll
      for (int ks = 0; ks < 4; ++ks) {
        u32 lo = (u32)f2b(sc[qh][ks][0]) | ((u32)f2b(sc[qh][ks][1]) << 16);
        u32 hi = (u32)f2b(sc[qh][ks][2]) | ((u32)f2b(sc[qh][ks][3]) << 16);
        const int chunk = (2 * ks + (lg >> 1)) ^ sw;
        char* p = psbase + row * 128 + chunk * 16 + (lg & 1) * 8;
        *(u32*)p = lo;
        *(u32*)(p + 4) = hi;
      }
    }
    // PV: A = P rows q (from Ps), B = V^T rows d (from Vs)
    bf16x8 pa[2][2];
#pragma unroll
    for (int qh = 0; qh < 2; ++qh) {
      const int row = qh * 16 + lr;
      const int sw = lr & 7;
      pa[qh][0] = *(const bf16x8*)(psbase + row * 128 + ((lg ^ sw) * 16));
      pa[qh][1] = *(const bf16x8*)(psbase + row * 128 + (((lg + 4) ^ sw) * 16));
    }
#pragma unroll
    for (int d4 = 0; d4 < 4; ++d4) {
      const int vrow = d4 * 16 + lr;
      const int sw = lr & 7;
      bf16x8 vf0 = *(const bf16x8*)&Vs[vrow * 64 + ((lg ^ sw) * 8)];
      bf16x8 vf1 = *(const bf16x8*)&Vs[vrow * 64 + (((lg + 4) ^ sw) * 8)];
      oacc[0][d4] = MFMA16(pa[0][0], vf0, oacc[0][d4]);
      oacc[0][d4] = MFMA16(pa[0][1], vf1, oacc[0][d4]);
      oacc[1][d4] = MFMA16(pa[1][0], vf0, oacc[1][d4]);
      oacc[1][d4] = MFMA16(pa[1][1], vf1, oacc[1][d4]);
    }
  }

  // epilogue: normalize and store
#pragma unroll
  for (int qh = 0; qh < 2; ++qh) {
    float lb[4];
#pragma unroll
    for (int r = 0; r < 4; ++r) lb[r] = __shfl(l[qh], (lane & 48) | (lg * 4 + r));
#pragma unroll
    for (int r = 0; r < 4; ++r) {
      float inv = 1.f / lb[r];
      int q = q0w + qh * 16 + lg * 4 + r;
      u16* orow = Ao + ((size_t)(b * 2048 + q)) * 1024 + h * 64 + lr;
#pragma unroll
      for (int d4 = 0; d4 < 4; ++d4) orow[d4 * 16] = f2b(oacc[qh][d4][r] * inv);
    }
  }
}

// ---------------- output projection (f32 out) ----------------
__global__ __launch_bounds__(256) void gemm_wo_k(const u16* __restrict__ Ab,
                                                 const u16* __restrict__ Wo,
                                                 float* __restrict__ Out) {
  __shared__ u16 As[128 * 32];
  __shared__ u16 Bs[128 * 32];
  const int mt = blockIdx.y, nt = blockIdx.x;
  const int tid = threadIdx.x, wave = tid >> 6, lane = tid & 63;
  const int wr = (wave >> 1) * 64, wc = (wave & 1) * 64;
  const int lr = lane & 15, lg = lane >> 4;
  const size_t arow = (size_t)(mt * 128 + wave * 32 + (lane >> 2)) * 1024 + (lane & 3) * 8;
  const size_t brow = (size_t)(nt * 128 + wave * 32 + (lane >> 2)) * 1024 + (lane & 3) * 8;
  u16* Ad0 = &As[(wave * 32) * 32];
  u16* Ad1 = &As[(wave * 32 + 16) * 32];
  u16* Bd0 = &Bs[(wave * 32) * 32];
  u16* Bd1 = &Bs[(wave * 32 + 16) * 32];

  f32x4 acc[4][4];
#pragma unroll
  for (int i = 0; i < 4; ++i)
#pragma unroll
    for (int j = 0; j < 4; ++j) acc[i][j] = (f32x4){0.f, 0.f, 0.f, 0.f};

  for (int kt = 0; kt < 1024; kt += 32) {
    glds16(Ab + arow + kt, Ad0);
    glds16(Ab + arow + kt + 16 * 1024, Ad1);
    glds16(Wo + brow + kt, Bd0);
    glds16(Wo + brow + kt + 16 * 1024, Bd1);
    __syncthreads();
    bf16x8 af[4], bfr[4];
#pragma unroll
    for (int mi = 0; mi < 4; ++mi)
      af[mi] = *(const bf16x8*)&As[(wr + mi * 16 + lr) * 32 + lg * 8];
#pragma unroll
    for (int ni = 0; ni < 4; ++ni)
      bfr[ni] = *(const bf16x8*)&Bs[(wc + ni * 16 + lr) * 32 + lg * 8];
#pragma unroll
    for (int mi = 0; mi < 4; ++mi)
#pragma unroll
      for (int ni = 0; ni < 4; ++ni)
        acc[mi][ni] = MFMA16(af[mi], bfr[ni], acc[mi][ni]);
    __syncthreads();
  }
#pragma unroll
  for (int mi = 0; mi < 4; ++mi)
#pragma unroll
    for (int ni = 0; ni < 4; ++ni) {
      int row0 = mt * 128 + wr + mi * 16 + lg * 4;
      int col = nt * 128 + wc + ni * 16 + lr;
#pragma unroll
      for (int r = 0; r < 4; ++r)
        Out[(size_t)(row0 + r) * 1024 + col] = acc[mi][ni][r];
    }
}

extern "C" void kernel_launch(void* const* d_in, const int* in_sizes, int n_in,
                              void* d_out, int out_size, void* d_ws, size_t ws_size,
                              hipStream_t stream) {
  const float* x = (const float*)d_in[0];
  const int* pos = (const int*)d_in[1];
  const float* wq = (const float*)d_in[2];
  const float* wk = (const float*)d_in[3];
  const float* wv = (const float*)d_in[4];
  const float* wo = (const float*)d_in[5];

  char* ws = (char*)d_ws;
  u16* xb = (u16*)ws;
  u16* wqb = xb + 8388608;
  u16* wkb = wqb + 1048576;
  u16* wvb = wkb + 1048576;
  u16* wob = wvb + 1048576;
  float2* tab = (float2*)(ws + 25165824);
  u16* Qp = (u16*)(ws + 27262976);
  u16* Kp = (u16*)(ws + 27262976 + 16777216);
  u16* Vt = (u16*)(ws + 27262976 + 2 * 16777216);
  u16* Ao = (u16*)(ws + 27262976 + 3 * 16777216);

  hipLaunchKernelGGL(cvt_k, dim3(12288), dim3(256), 0, stream, x, wq, wk, wv, wo, xb);
  hipLaunchKernelGGL(rope_tab_k, dim3(1024), dim3(256), 0, stream, pos, tab);
  hipLaunchKernelGGL(gemm_qkv_k, dim3(8, 64, 3), dim3(256), 0, stream, xb, wqb, wkb, wvb,
                     Qp, Kp, Vt);
  hipLaunchKernelGGL(rope_k, dim3(32768), dim3(256), 0, stream, Qp, Kp, tab);
  hipLaunchKernelGGL(fattn_k, dim3(1024), dim3(256), 0, stream, Qp, Kp, Vt, Ao);
  hipLaunchKernelGGL(gemm_wo_k, dim3(8, 64), dim3(256), 0, stream, Ao, wob, (float*)d_out);
}

// Round 3
// 209.721 us; speedup vs baseline: 1.9549x; 1.0723x over previous
//
#include <hip/hip_runtime.h>

typedef __bf16 bf16x8 __attribute__((ext_vector_type(8)));
typedef __bf16 bf16x2 __attribute__((ext_vector_type(2)));
typedef float f32x4 __attribute__((ext_vector_type(4)));
typedef unsigned short u16;
typedef unsigned int u32;

#define MFMA16(a, b, c) __builtin_amdgcn_mfma_f32_16x16x32_bf16((a), (b), (c), 0, 0, 0)

__device__ __forceinline__ u16 f2b(float f) {
  u32 u = __float_as_uint(f);
  u += 0x7FFFu + ((u >> 16) & 1u);
  return (u16)(u >> 16);
}
__device__ __forceinline__ float b2f(u16 h) { return __uint_as_float(((u32)h) << 16); }

__device__ __forceinline__ u32 pkbf(float a, float b) {
  bf16x2 h = {(__bf16)a, (__bf16)b};  // compiler emits v_cvt_pk_bf16_f32
  return __builtin_bit_cast(u32, h);
}

__device__ __forceinline__ float exp2_(float x) {
#if __has_builtin(__builtin_amdgcn_exp2f)
  return __builtin_amdgcn_exp2f(x);
#else
  return exp2f(x);
#endif
}

__device__ __forceinline__ void glds16(const void* g, void* l) {
  __builtin_amdgcn_global_load_lds((const __attribute__((address_space(1))) void*)g,
                                   (__attribute__((address_space(3))) void*)l, 16, 0, 0);
}

// ---------------- f32 -> bf16 conversion: x (8.4M) then WQ,WK,WV,WO (1M each) ----------------
__global__ __launch_bounds__(256) void cvt_k(const float* __restrict__ x,
                                             const float* __restrict__ wq,
                                             const float* __restrict__ wk,
                                             const float* __restrict__ wv,
                                             const float* __restrict__ wo,
                                             u16* __restrict__ dst) {
  size_t e = ((size_t)blockIdx.x * 256 + threadIdx.x) * 4;
  const float* src;
  size_t off;
  if (e < 8388608ull) {
    src = x; off = e;
  } else {
    size_t r = e - 8388608ull;
    u32 wi = (u32)(r >> 20);
    off = r & 1048575ull;
    src = (wi == 0) ? wq : (wi == 1) ? wk : (wi == 2) ? wv : wo;
  }
  float4 v = *(const float4*)(src + off);
  ushort4 o = make_ushort4(f2b(v.x), f2b(v.y), f2b(v.z), f2b(v.w));
  *(ushort4*)(dst + e) = o;
}

// ---------------- RoPE cos/sin table: tab[row*32+j] ----------------
__global__ __launch_bounds__(256) void rope_tab_k(const int* __restrict__ pos,
                                                  float2* __restrict__ tab) {
  int i = blockIdx.x * 256 + threadIdx.x;  // 262144 total
  int row = i >> 5, j = i & 31;
  float p = (float)pos[row];
  float inv = exp2f((float)j * -0.41524101186092029f);  // 10000^(-j/32)
  float s, c;
  sincosf(p * inv, &s, &c);
  tab[i] = make_float2(c, s);
}

// ---------------- QKV projection GEMM with fused RoPE epilogue ----------------
// Q is additionally scaled by 0.125*log2(e) (exp2-space softmax downstream).
__global__ __launch_bounds__(256) void gemm_qkv_k(const u16* __restrict__ Xb,
                                                  const u16* __restrict__ Wq,
                                                  const u16* __restrict__ Wk,
                                                  const u16* __restrict__ Wv,
                                                  const float2* __restrict__ tab,
                                                  u16* __restrict__ Qp,
                                                  u16* __restrict__ Kp,
                                                  u16* __restrict__ Vt) {
  __shared__ u16 As[128 * 32];
  __shared__ u16 Bs[128 * 32];
  const int z = blockIdx.z;
  const u16* W = (z == 0) ? Wq : (z == 1) ? Wk : Wv;
  const int mt = blockIdx.y, nt = blockIdx.x;
  const int tid = threadIdx.x, wave = tid >> 6, lane = tid & 63;
  const int wr = (wave >> 1) * 64, wc = (wave & 1) * 64;
  const int lr = lane & 15, lg = lane >> 4;

  const size_t arow = (size_t)(mt * 128 + wave * 32 + (lane >> 2)) * 1024 + (lane & 3) * 8;
  const size_t brow = (size_t)(nt * 128 + wave * 32 + (lane >> 2)) * 1024 + (lane & 3) * 8;
  u16* Ad0 = &As[(wave * 32) * 32];
  u16* Ad1 = &As[(wave * 32 + 16) * 32];
  u16* Bd0 = &Bs[(wave * 32) * 32];
  u16* Bd1 = &Bs[(wave * 32 + 16) * 32];

  f32x4 acc[4][4];
#pragma unroll
  for (int i = 0; i < 4; ++i)
#pragma unroll
    for (int j = 0; j < 4; ++j) acc[i][j] = (f32x4){0.f, 0.f, 0.f, 0.f};

  for (int kt = 0; kt < 1024; kt += 32) {
    glds16(Xb + arow + kt, Ad0);
    glds16(Xb + arow + kt + 16 * 1024, Ad1);
    glds16(W + brow + kt, Bd0);
    glds16(W + brow + kt + 16 * 1024, Bd1);
    __syncthreads();
    bf16x8 af[4], bfr[4];
#pragma unroll
    for (int mi = 0; mi < 4; ++mi)
      af[mi] = *(const bf16x8*)&As[(wr + mi * 16 + lr) * 32 + lg * 8];
#pragma unroll
    for (int ni = 0; ni < 4; ++ni)
      bfr[ni] = *(const bf16x8*)&Bs[(wc + ni * 16 + lr) * 32 + lg * 8];
#pragma unroll
    for (int mi = 0; mi < 4; ++mi)
#pragma unroll
      for (int ni = 0; ni < 4; ++ni)
        acc[mi][ni] = MFMA16(af[mi], bfr[ni], acc[mi][ni]);
    __syncthreads();
  }

  if (z < 2) {
    // fused RoPE: pair partner lives in adjacent lane (col ^ 1)
    u16* out = (z == 0) ? Qp : Kp;
    const float scl = (z == 0) ? 0.18033688011112043f : 1.0f;  // 0.125*log2(e) for Q
#pragma unroll
    for (int mi = 0; mi < 4; ++mi)
#pragma unroll
      for (int ni = 0; ni < 4; ++ni) {
        int row0 = mt * 128 + wr + mi * 16 + lg * 4;
        int col = nt * 128 + wc + ni * 16 + lr;
        int j = (col >> 1) & 31;
        float sgn = (col & 1) ? 1.f : -1.f;
#pragma unroll
        for (int r = 0; r < 4; ++r) {
          float self = acc[mi][ni][r];
          float partner = __shfl_xor(self, 1);
          float2 cs = tab[(size_t)(row0 + r) * 32 + j];
          float o = (self * cs.x + partner * cs.y * sgn) * scl;
          out[(size_t)(row0 + r) * 1024 + col] = f2b(o);
        }
      }
  } else {
#pragma unroll
    for (int mi = 0; mi < 4; ++mi)
#pragma unroll
      for (int ni = 0; ni < 4; ++ni) {
        int row0 = mt * 128 + wr + mi * 16 + lg * 4;
        int e = nt * 128 + wc + ni * 16 + lr;
        int b = row0 >> 11, s = row0 & 2047;
        ushort4 pk = make_ushort4(f2b(acc[mi][ni][0]), f2b(acc[mi][ni][1]),
                                  f2b(acc[mi][ni][2]), f2b(acc[mi][ni][3]));
        *(ushort4*)&Vt[((size_t)(b * 1024 + e)) * 2048 + s] = pk;
      }
  }
}

// ---------------- causal flash attention ----------------
// Double-buffered K/V staging (1 barrier/step), exp2-space softmax with defer-max,
// cvt_pk P-pack. XOR-swizzled LDS. 4 waves x 32 q-rows, KVBLK=64.
__global__ __launch_bounds__(256) void fattn_k(const u16* __restrict__ Qp,
                                               const u16* __restrict__ Kp,
                                               const u16* __restrict__ Vt,
                                               u16* __restrict__ Ao) {
  __shared__ u16 Ks[2][64 * 64];    // [buf][kv][d], swizzled
  __shared__ u16 Vs[2][64 * 64];    // [buf][d][kv], swizzled
  __shared__ u16 Ps[4][32 * 64];    // per-wave [q][kv], swizzled
  const int blk = blockIdx.x;
  const int g = blk & 7, jj = blk >> 3;
  const int bh = g * 8 + (jj & 7);
  const int qt = 15 - (jj >> 3);    // long blocks first
  const int b = bh >> 4, h = bh & 15;
  const int tid = threadIdx.x, wave = tid >> 6, lane = tid & 63;
  const int lr = lane & 15, lg = lane >> 4;
  const int q0w = qt * 128 + wave * 32;

  bf16x8 qf[2][2];
#pragma unroll
  for (int qh = 0; qh < 2; ++qh) {
    const u16* qb = Qp + ((size_t)(b * 2048 + q0w + qh * 16 + lr)) * 1024 + h * 64 + lg * 8;
    qf[qh][0] = *(const bf16x8*)qb;
    qf[qh][1] = *(const bf16x8*)(qb + 32);
  }

  float m[2], l[2];
  f32x4 oacc[2][4];
#pragma unroll
  for (int qh = 0; qh < 2; ++qh) {
    m[qh] = -1e30f; l[qh] = 0.f;
#pragma unroll
    for (int d4 = 0; d4 < 4; ++d4) oacc[qh][d4] = (f32x4){0.f, 0.f, 0.f, 0.f};
  }

  // staging: wave w stages rows [16w,16w+16); source chunk pre-swizzled by row&7
  const int srow = lane >> 3;
  const int schunk = (lane & 7) ^ srow;
  const u16* kbase = Kp + ((size_t)(b * 2048 + 16 * wave + srow)) * 1024 + h * 64 + schunk * 8;
  const u16* vbase = Vt + ((size_t)(b * 1024 + h * 64 + 16 * wave + srow)) * 2048 + schunk * 8;
  char* psbase = (char*)&Ps[wave][0];

  const int ktmax = 2 * qt + 1;
  const int ktmask = q0w >> 6;
  const int ktneed = 2 * qt + (wave >> 1);

  // prologue: stage kt=0 into buf 0
  glds16(kbase, &Ks[0][(16 * wave) * 64]);
  glds16(kbase + 8192, &Ks[0][(16 * wave + 8) * 64]);
  glds16(vbase, &Vs[0][(16 * wave) * 64]);
  glds16(vbase + 16384, &Vs[0][(16 * wave + 8) * 64]);

  int cur = 0;
  for (int kt = 0; kt <= ktmax; ++kt, cur ^= 1) {
    __syncthreads();  // drains stage(kt); protects buf cur^1 reuse
    if (kt < ktmax) {
      const int nx = cur ^ 1, k1 = kt + 1;
      glds16(kbase + (size_t)k1 * 65536, &Ks[nx][(16 * wave) * 64]);
      glds16(kbase + (size_t)k1 * 65536 + 8192, &Ks[nx][(16 * wave + 8) * 64]);
      glds16(vbase + k1 * 64, &Vs[nx][(16 * wave) * 64]);
      glds16(vbase + k1 * 64 + 16384, &Vs[nx][(16 * wave + 8) * 64]);
    }
    if (kt > ktneed) continue;
    const u16* KB = &Ks[cur][0];
    const u16* VB = &Vs[cur][0];

    // QK^T swapped: lane holds kv = ks*16+lg*4+r for q = q0w+qh*16+lr
    f32x4 sc[2][4];
#pragma unroll
    for (int ks = 0; ks < 4; ++ks) {
      const int krow = ks * 16 + lr;
      const int sw = lr & 7;
      bf16x8 kf0 = *(const bf16x8*)&KB[krow * 64 + ((lg ^ sw) * 8)];
      bf16x8 kf1 = *(const bf16x8*)&KB[krow * 64 + (((lg + 4) ^ sw) * 8)];
#pragma unroll
      for (int qh = 0; qh < 2; ++qh) {
        f32x4 s = (f32x4){0.f, 0.f, 0.f, 0.f};
        s = MFMA16(kf0, qf[qh][0], s);
        s = MFMA16(kf1, qf[qh][1], s);
        sc[qh][ks] = s;
      }
    }
    if (kt >= ktmask) {  // causal mask
#pragma unroll
      for (int qh = 0; qh < 2; ++qh) {
        int q = q0w + qh * 16 + lr;
#pragma unroll
        for (int ks = 0; ks < 4; ++ks)
#pragma unroll
          for (int r = 0; r < 4; ++r) {
            int kv = kt * 64 + ks * 16 + lg * 4 + r;
            if (kv > q) sc[qh][ks][r] = -__builtin_inff();
          }
      }
    }

    // online softmax in log2 space, defer-max THR=8
#pragma unroll
    for (int qh = 0; qh < 2; ++qh) {
      float pm = sc[qh][0][0];
#pragma unroll
      for (int ks = 0; ks < 4; ++ks)
#pragma unroll
        for (int r = 0; r < 4; ++r) pm = fmaxf(pm, sc[qh][ks][r]);
      pm = fmaxf(pm, __shfl_xor(pm, 16));
      pm = fmaxf(pm, __shfl_xor(pm, 32));
      if (__any(pm > m[qh] + 8.f)) {
        float mn = fmaxf(m[qh], pm);
        float corr = exp2_(m[qh] - mn);
        m[qh] = mn;
        l[qh] *= corr;
        float cb[4];
#pragma unroll
        for (int r = 0; r < 4; ++r) cb[r] = __shfl(corr, (lane & 48) | (lg * 4 + r));
#pragma unroll
        for (int d4 = 0; d4 < 4; ++d4)
#pragma unroll
          for (int r = 0; r < 4; ++r) oacc[qh][d4][r] *= cb[r];
      }
      float rs = 0.f;
#pragma unroll
      for (int ks = 0; ks < 4; ++ks)
#pragma unroll
        for (int r = 0; r < 4; ++r) {
          float p = exp2_(sc[qh][ks][r] - m[qh]);
          sc[qh][ks][r] = p;
          rs += p;
        }
      rs += __shfl_xor(rs, 16);
      rs += __shfl_xor(rs, 32);
      l[qh] += rs;
    }

    // P -> bf16 (cvt_pk) -> swizzled per-wave LDS tile [q][kv]
#pragma unroll
    for (int qh = 0; qh < 2; ++qh) {
      const int row = qh * 16 + lr;
      const int sw = lr & 7;
#pragma unroll
      for (int ks = 0; ks < 4; ++ks) {
        const int chunk = (2 * ks + (lg >> 1)) ^ sw;
        char* p = psbase + row * 128 + chunk * 16 + (lg & 1) * 8;
        *(uint2*)p = make_uint2(pkbf(sc[qh][ks][0], sc[qh][ks][1]),
                                pkbf(sc[qh][ks][2], sc[qh][ks][3]));
      }
    }
    // PV
    bf16x8 pa[2][2];
#pragma unroll
    for (int qh = 0; qh < 2; ++qh) {
      const int row = qh * 16 + lr;
      const int sw = lr & 7;
      pa[qh][0] = *(const bf16x8*)(psbase + row * 128 + ((lg ^ sw) * 16));
      pa[qh][1] = *(const bf16x8*)(psbase + row * 128 + (((lg + 4) ^ sw) * 16));
    }
#pragma unroll
    for (int d4 = 0; d4 < 4; ++d4) {
      const int vrow = d4 * 16 + lr;
      const int sw = lr & 7;
      bf16x8 vf0 = *(const bf16x8*)&VB[vrow * 64 + ((lg ^ sw) * 8)];
      bf16x8 vf1 = *(const bf16x8*)&VB[vrow * 64 + (((lg + 4) ^ sw) * 8)];
      oacc[0][d4] = MFMA16(pa[0][0], vf0, oacc[0][d4]);
      oacc[0][d4] = MFMA16(pa[0][1], vf1, oacc[0][d4]);
      oacc[1][d4] = MFMA16(pa[1][0], vf0, oacc[1][d4]);
      oacc[1][d4] = MFMA16(pa[1][1], vf1, oacc[1][d4]);
    }
  }

  // epilogue: normalize and store
#pragma unroll
  for (int qh = 0; qh < 2; ++qh) {
    float lb[4];
#pragma unroll
    for (int r = 0; r < 4; ++r) lb[r] = __shfl(l[qh], (lane & 48) | (lg * 4 + r));
#pragma unroll
    for (int r = 0; r < 4; ++r) {
      float inv = 1.f / lb[r];
      int q = q0w + qh * 16 + lg * 4 + r;
      u16* orow = Ao + ((size_t)(b * 2048 + q)) * 1024 + h * 64 + lr;
#pragma unroll
      for (int d4 = 0; d4 < 4; ++d4) orow[d4 * 16] = f2b(oacc[qh][d4][r] * inv);
    }
  }
}

// ---------------- output projection (f32 out) ----------------
__global__ __launch_bounds__(256) void gemm_wo_k(const u16* __restrict__ Ab,
                                                 const u16* __restrict__ Wo,
                                                 float* __restrict__ Out) {
  __shared__ u16 As[128 * 32];
  __shared__ u16 Bs[128 * 32];
  const int mt = blockIdx.y, nt = blockIdx.x;
  const int tid = threadIdx.x, wave = tid >> 6, lane = tid & 63;
  const int wr = (wave >> 1) * 64, wc = (wave & 1) * 64;
  const int lr = lane & 15, lg = lane >> 4;
  const size_t arow = (size_t)(mt * 128 + wave * 32 + (lane >> 2)) * 1024 + (lane & 3) * 8;
  const size_t brow = (size_t)(nt * 128 + wave * 32 + (lane >> 2)) * 1024 + (lane & 3) * 8;
  u16* Ad0 = &As[(wave * 32) * 32];
  u16* Ad1 = &As[(wave * 32 + 16) * 32];
  u16* Bd0 = &Bs[(wave * 32) * 32];
  u16* Bd1 = &Bs[(wave * 32 + 16) * 32];

  f32x4 acc[4][4];
#pragma unroll
  for (int i = 0; i < 4; ++i)
#pragma unroll
    for (int j = 0; j < 4; ++j) acc[i][j] = (f32x4){0.f, 0.f, 0.f, 0.f};

  for (int kt = 0; kt < 1024; kt += 32) {
    glds16(Ab + arow + kt, Ad0);
    glds16(Ab + arow + kt + 16 * 1024, Ad1);
    glds16(Wo + brow + kt, Bd0);
    glds16(Wo + brow + kt + 16 * 1024, Bd1);
    __syncthreads();
    bf16x8 af[4], bfr[4];
#pragma unroll
    for (int mi = 0; mi < 4; ++mi)
      af[mi] = *(const bf16x8*)&As[(wr + mi * 16 + lr) * 32 + lg * 8];
#pragma unroll
    for (int ni = 0; ni < 4; ++ni)
      bfr[ni] = *(const bf16x8*)&Bs[(wc + ni * 16 + lr) * 32 + lg * 8];
#pragma unroll
    for (int mi = 0; mi < 4; ++mi)
#pragma unroll
      for (int ni = 0; ni < 4; ++ni)
        acc[mi][ni] = MFMA16(af[mi], bfr[ni], acc[mi][ni]);
    __syncthreads();
  }
#pragma unroll
  for (int mi = 0; mi < 4; ++mi)
#pragma unroll
    for (int ni = 0; ni < 4; ++ni) {
      int row0 = mt * 128 + wr + mi * 16 + lg * 4;
      int col = nt * 128 + wc + ni * 16 + lr;
#pragma unroll
      for (int r = 0; r < 4; ++r)
        Out[(size_t)(row0 + r) * 1024 + col] = acc[mi][ni][r];
    }
}

extern "C" void kernel_launch(void* const* d_in, const int* in_sizes, int n_in,
                              void* d_out, int out_size, void* d_ws, size_t ws_size,
                              hipStream_t stream) {
  const float* x = (const float*)d_in[0];
  const int* pos = (const int*)d_in[1];
  const float* wq = (const float*)d_in[2];
  const float* wk = (const float*)d_in[3];
  const float* wv = (const float*)d_in[4];
  const float* wo = (const float*)d_in[5];

  char* ws = (char*)d_ws;
  u16* xb = (u16*)ws;
  u16* wqb = xb + 8388608;
  u16* wkb = wqb + 1048576;
  u16* wvb = wkb + 1048576;
  u16* wob = wvb + 1048576;
  float2* tab = (float2*)(ws + 25165824);
  u16* Qp = (u16*)(ws + 27262976);
  u16* Kp = (u16*)(ws + 27262976 + 16777216);
  u16* Vt = (u16*)(ws + 27262976 + 2 * 16777216);
  u16* Ao = (u16*)(ws + 27262976 + 3 * 16777216);

  hipLaunchKernelGGL(cvt_k, dim3(12288), dim3(256), 0, stream, x, wq, wk, wv, wo, xb);
  hipLaunchKernelGGL(rope_tab_k, dim3(1024), dim3(256), 0, stream, pos, tab);
  hipLaunchKernelGGL(gemm_qkv_k, dim3(8, 64, 3), dim3(256), 0, stream, xb, wqb, wkb, wvb,
                     tab, Qp, Kp, Vt);
  hipLaunchKernelGGL(fattn_k, dim3(1024), dim3(256), 0, stream, Qp, Kp, Vt, Ao);
  hipLaunchKernelGGL(gemm_wo_k, dim3(8, 64), dim3(256), 0, stream, Ao, wob, (float*)d_out);
}

// Round 4
// 199.004 us; speedup vs baseline: 2.0602x; 1.0539x over previous
//
#include <hip/hip_runtime.h>

typedef __bf16 bf16x8 __attribute__((ext_vector_type(8)));
typedef __bf16 bf16x2 __attribute__((ext_vector_type(2)));
typedef float f32x4 __attribute__((ext_vector_type(4)));
typedef unsigned short u16;
typedef unsigned int u32;

#define MFMA16(a, b, c) __builtin_amdgcn_mfma_f32_16x16x32_bf16((a), (b), (c), 0, 0, 0)

__device__ __forceinline__ u16 f2b(float f) {
  u32 u = __float_as_uint(f);
  u += 0x7FFFu + ((u >> 16) & 1u);
  return (u16)(u >> 16);
}
__device__ __forceinline__ float b2f(u16 h) { return __uint_as_float(((u32)h) << 16); }

__device__ __forceinline__ u32 pkbf(float a, float b) {
  bf16x2 h = {(__bf16)a, (__bf16)b};  // compiler emits v_cvt_pk_bf16_f32
  return __builtin_bit_cast(u32, h);
}

__device__ __forceinline__ float exp2_(float x) {
#if __has_builtin(__builtin_amdgcn_exp2f)
  return __builtin_amdgcn_exp2f(x);
#else
  return exp2f(x);
#endif
}

__device__ __forceinline__ void glds16(const void* g, void* l) {
  __builtin_amdgcn_global_load_lds((const __attribute__((address_space(1))) void*)g,
                                   (__attribute__((address_space(3))) void*)l, 16, 0, 0);
}

// ---------------- f32 -> bf16 conversion: x (8.4M) then WQ,WK,WV,WO (1M each) ----------------
__global__ __launch_bounds__(256) void cvt_k(const float* __restrict__ x,
                                             const float* __restrict__ wq,
                                             const float* __restrict__ wk,
                                             const float* __restrict__ wv,
                                             const float* __restrict__ wo,
                                             u16* __restrict__ dst) {
  size_t e = ((size_t)blockIdx.x * 256 + threadIdx.x) * 4;
  const float* src;
  size_t off;
  if (e < 8388608ull) {
    src = x; off = e;
  } else {
    size_t r = e - 8388608ull;
    u32 wi = (u32)(r >> 20);
    off = r & 1048575ull;
    src = (wi == 0) ? wq : (wi == 1) ? wk : (wi == 2) ? wv : wo;
  }
  float4 v = *(const float4*)(src + off);
  ushort4 o = make_ushort4(f2b(v.x), f2b(v.y), f2b(v.z), f2b(v.w));
  *(ushort4*)(dst + e) = o;
}

// ---------------- RoPE cos/sin table: tab[row*32+j] ----------------
__global__ __launch_bounds__(256) void rope_tab_k(const int* __restrict__ pos,
                                                  float2* __restrict__ tab) {
  int i = blockIdx.x * 256 + threadIdx.x;  // 262144 total
  int row = i >> 5, j = i & 31;
  float p = (float)pos[row];
  float inv = exp2f((float)j * -0.41524101186092029f);  // 10000^(-j/32)
  float s, c;
  sincosf(p * inv, &s, &c);
  tab[i] = make_float2(c, s);
}

// ---------------- QKV projection GEMM with fused RoPE epilogue ----------------
// 1536 blocks, XCD-chunked: xcd = wgid&7 owns 24 consecutive (z,mt) panels;
// the 8 nt-blocks of a panel are consecutive -> same XCD -> A-panel L2-hit.
__global__ __launch_bounds__(256) void gemm_qkv_k(const u16* __restrict__ Xb,
                                                  const u16* __restrict__ Wq,
                                                  const u16* __restrict__ Wk,
                                                  const u16* __restrict__ Wv,
                                                  const float2* __restrict__ tab,
                                                  u16* __restrict__ Qp,
                                                  u16* __restrict__ Kp,
                                                  u16* __restrict__ Vt) {
  __shared__ u16 As[128 * 32];
  __shared__ u16 Bs[128 * 32];
  const int wgid = blockIdx.x;
  const int xcd = wgid & 7;
  const int idx = wgid >> 3;               // 0..191
  const int panel = xcd * 24 + (idx >> 3); // 0..191 (z-major)
  const int nt = idx & 7;
  const int z = panel >> 6;
  const int mt = panel & 63;
  const u16* W = (z == 0) ? Wq : (z == 1) ? Wk : Wv;
  const int tid = threadIdx.x, wave = tid >> 6, lane = tid & 63;
  const int wr = (wave >> 1) * 64, wc = (wave & 1) * 64;
  const int lr = lane & 15, lg = lane >> 4;

  const size_t arow = (size_t)(mt * 128 + wave * 32 + (lane >> 2)) * 1024 + (lane & 3) * 8;
  const size_t brow = (size_t)(nt * 128 + wave * 32 + (lane >> 2)) * 1024 + (lane & 3) * 8;
  u16* Ad0 = &As[(wave * 32) * 32];
  u16* Ad1 = &As[(wave * 32 + 16) * 32];
  u16* Bd0 = &Bs[(wave * 32) * 32];
  u16* Bd1 = &Bs[(wave * 32 + 16) * 32];

  f32x4 acc[4][4];
#pragma unroll
  for (int i = 0; i < 4; ++i)
#pragma unroll
    for (int j = 0; j < 4; ++j) acc[i][j] = (f32x4){0.f, 0.f, 0.f, 0.f};

  for (int kt = 0; kt < 1024; kt += 32) {
    glds16(Xb + arow + kt, Ad0);
    glds16(Xb + arow + kt + 16 * 1024, Ad1);
    glds16(W + brow + kt, Bd0);
    glds16(W + brow + kt + 16 * 1024, Bd1);
    __syncthreads();
    bf16x8 af[4], bfr[4];
#pragma unroll
    for (int mi = 0; mi < 4; ++mi)
      af[mi] = *(const bf16x8*)&As[(wr + mi * 16 + lr) * 32 + lg * 8];
#pragma unroll
    for (int ni = 0; ni < 4; ++ni)
      bfr[ni] = *(const bf16x8*)&Bs[(wc + ni * 16 + lr) * 32 + lg * 8];
#pragma unroll
    for (int mi = 0; mi < 4; ++mi)
#pragma unroll
      for (int ni = 0; ni < 4; ++ni)
        acc[mi][ni] = MFMA16(af[mi], bfr[ni], acc[mi][ni]);
    __syncthreads();
  }

  if (z < 2) {
    // fused RoPE: pair partner lives in adjacent lane (col ^ 1)
    u16* out = (z == 0) ? Qp : Kp;
    const float scl = (z == 0) ? 0.18033688011112043f : 1.0f;  // 0.125*log2(e) for Q
#pragma unroll
    for (int mi = 0; mi < 4; ++mi)
#pragma unroll
      for (int ni = 0; ni < 4; ++ni) {
        int row0 = mt * 128 + wr + mi * 16 + lg * 4;
        int col = nt * 128 + wc + ni * 16 + lr;
        int j = (col >> 1) & 31;
        float sgn = (col & 1) ? 1.f : -1.f;
#pragma unroll
        for (int r = 0; r < 4; ++r) {
          float self = acc[mi][ni][r];
          float partner = __shfl_xor(self, 1);
          float2 cs = tab[(size_t)(row0 + r) * 32 + j];
          float o = (self * cs.x + partner * cs.y * sgn) * scl;
          out[(size_t)(row0 + r) * 1024 + col] = f2b(o);
        }
      }
  } else {
#pragma unroll
    for (int mi = 0; mi < 4; ++mi)
#pragma unroll
      for (int ni = 0; ni < 4; ++ni) {
        int row0 = mt * 128 + wr + mi * 16 + lg * 4;
        int e = nt * 128 + wc + ni * 16 + lr;
        int b = row0 >> 11, s = row0 & 2047;
        ushort4 pk = make_ushort4(f2b(acc[mi][ni][0]), f2b(acc[mi][ni][1]),
                                  f2b(acc[mi][ni][2]), f2b(acc[mi][ni][3]));
        *(ushort4*)&Vt[((size_t)(b * 1024 + e)) * 2048 + s] = pk;
      }
  }
}

// ---------------- causal flash attention ----------------
__global__ __launch_bounds__(256) void fattn_k(const u16* __restrict__ Qp,
                                               const u16* __restrict__ Kp,
                                               const u16* __restrict__ Vt,
                                               u16* __restrict__ Ao) {
  __shared__ u16 Ks[2][64 * 64];    // [buf][kv][d], swizzled
  __shared__ u16 Vs[2][64 * 64];    // [buf][d][kv], swizzled
  __shared__ u16 Ps[4][32 * 64];    // per-wave [q][kv], swizzled
  const int blk = blockIdx.x;
  const int g = blk & 7, jj = blk >> 3;
  const int bh = g * 8 + (jj & 7);
  const int qt = 15 - (jj >> 3);    // long blocks first
  const int b = bh >> 4, h = bh & 15;
  const int tid = threadIdx.x, wave = tid >> 6, lane = tid & 63;
  const int lr = lane & 15, lg = lane >> 4;
  const int q0w = qt * 128 + wave * 32;

  bf16x8 qf[2][2];
#pragma unroll
  for (int qh = 0; qh < 2; ++qh) {
    const u16* qb = Qp + ((size_t)(b * 2048 + q0w + qh * 16 + lr)) * 1024 + h * 64 + lg * 8;
    qf[qh][0] = *(const bf16x8*)qb;
    qf[qh][1] = *(const bf16x8*)(qb + 32);
  }

  float m[2], l[2];
  f32x4 oacc[2][4];
#pragma unroll
  for (int qh = 0; qh < 2; ++qh) {
    m[qh] = -1e30f; l[qh] = 0.f;
#pragma unroll
    for (int d4 = 0; d4 < 4; ++d4) oacc[qh][d4] = (f32x4){0.f, 0.f, 0.f, 0.f};
  }

  const int srow = lane >> 3;
  const int schunk = (lane & 7) ^ srow;
  const u16* kbase = Kp + ((size_t)(b * 2048 + 16 * wave + srow)) * 1024 + h * 64 + schunk * 8;
  const u16* vbase = Vt + ((size_t)(b * 1024 + h * 64 + 16 * wave + srow)) * 2048 + schunk * 8;
  char* psbase = (char*)&Ps[wave][0];

  const int ktmax = 2 * qt + 1;
  const int ktmask = q0w >> 6;
  const int ktneed = 2 * qt + (wave >> 1);

  glds16(kbase, &Ks[0][(16 * wave) * 64]);
  glds16(kbase + 8192, &Ks[0][(16 * wave + 8) * 64]);
  glds16(vbase, &Vs[0][(16 * wave) * 64]);
  glds16(vbase + 16384, &Vs[0][(16 * wave + 8) * 64]);

  int cur = 0;
  for (int kt = 0; kt <= ktmax; ++kt, cur ^= 1) {
    __syncthreads();
    if (kt < ktmax) {
      const int nx = cur ^ 1, k1 = kt + 1;
      glds16(kbase + (size_t)k1 * 65536, &Ks[nx][(16 * wave) * 64]);
      glds16(kbase + (size_t)k1 * 65536 + 8192, &Ks[nx][(16 * wave + 8) * 64]);
      glds16(vbase + k1 * 64, &Vs[nx][(16 * wave) * 64]);
      glds16(vbase + k1 * 64 + 16384, &Vs[nx][(16 * wave + 8) * 64]);
    }
    if (kt > ktneed) continue;
    const u16* KB = &Ks[cur][0];
    const u16* VB = &Vs[cur][0];

    f32x4 sc[2][4];
#pragma unroll
    for (int ks = 0; ks < 4; ++ks) {
      const int krow = ks * 16 + lr;
      const int sw = lr & 7;
      bf16x8 kf0 = *(const bf16x8*)&KB[krow * 64 + ((lg ^ sw) * 8)];
      bf16x8 kf1 = *(const bf16x8*)&KB[krow * 64 + (((lg + 4) ^ sw) * 8)];
#pragma unroll
      for (int qh = 0; qh < 2; ++qh) {
        f32x4 s = (f32x4){0.f, 0.f, 0.f, 0.f};
        s = MFMA16(kf0, qf[qh][0], s);
        s = MFMA16(kf1, qf[qh][1], s);
        sc[qh][ks] = s;
      }
    }
    if (kt >= ktmask) {
#pragma unroll
      for (int qh = 0; qh < 2; ++qh) {
        int q = q0w + qh * 16 + lr;
#pragma unroll
        for (int ks = 0; ks < 4; ++ks)
#pragma unroll
          for (int r = 0; r < 4; ++r) {
            int kv = kt * 64 + ks * 16 + lg * 4 + r;
            if (kv > q) sc[qh][ks][r] = -__builtin_inff();
          }
      }
    }

#pragma unroll
    for (int qh = 0; qh < 2; ++qh) {
      float pm = sc[qh][0][0];
#pragma unroll
      for (int ks = 0; ks < 4; ++ks)
#pragma unroll
        for (int r = 0; r < 4; ++r) pm = fmaxf(pm, sc[qh][ks][r]);
      pm = fmaxf(pm, __shfl_xor(pm, 16));
      pm = fmaxf(pm, __shfl_xor(pm, 32));
      if (__any(pm > m[qh] + 8.f)) {
        float mn = fmaxf(m[qh], pm);
        float corr = exp2_(m[qh] - mn);
        m[qh] = mn;
        l[qh] *= corr;
        float cb[4];
#pragma unroll
        for (int r = 0; r < 4; ++r) cb[r] = __shfl(corr, (lane & 48) | (lg * 4 + r));
#pragma unroll
        for (int d4 = 0; d4 < 4; ++d4)
#pragma unroll
          for (int r = 0; r < 4; ++r) oacc[qh][d4][r] *= cb[r];
      }
      float rs = 0.f;
#pragma unroll
      for (int ks = 0; ks < 4; ++ks)
#pragma unroll
        for (int r = 0; r < 4; ++r) {
          float p = exp2_(sc[qh][ks][r] - m[qh]);
          sc[qh][ks][r] = p;
          rs += p;
        }
      rs += __shfl_xor(rs, 16);
      rs += __shfl_xor(rs, 32);
      l[qh] += rs;
    }

#pragma unroll
    for (int qh = 0; qh < 2; ++qh) {
      const int row = qh * 16 + lr;
      const int sw = lr & 7;
#pragma unroll
      for (int ks = 0; ks < 4; ++ks) {
        const int chunk = (2 * ks + (lg >> 1)) ^ sw;
        char* p = psbase + row * 128 + chunk * 16 + (lg & 1) * 8;
        *(uint2*)p = make_uint2(pkbf(sc[qh][ks][0], sc[qh][ks][1]),
                                pkbf(sc[qh][ks][2], sc[qh][ks][3]));
      }
    }
    bf16x8 pa[2][2];
#pragma unroll
    for (int qh = 0; qh < 2; ++qh) {
      const int row = qh * 16 + lr;
      const int sw = lr & 7;
      pa[qh][0] = *(const bf16x8*)(psbase + row * 128 + ((lg ^ sw) * 16));
      pa[qh][1] = *(const bf16x8*)(psbase + row * 128 + (((lg + 4) ^ sw) * 16));
    }
#pragma unroll
    for (int d4 = 0; d4 < 4; ++d4) {
      const int vrow = d4 * 16 + lr;
      const int sw = lr & 7;
      bf16x8 vf0 = *(const bf16x8*)&VB[vrow * 64 + ((lg ^ sw) * 8)];
      bf16x8 vf1 = *(const bf16x8*)&VB[vrow * 64 + (((lg + 4) ^ sw) * 8)];
      oacc[0][d4] = MFMA16(pa[0][0], vf0, oacc[0][d4]);
      oacc[0][d4] = MFMA16(pa[0][1], vf1, oacc[0][d4]);
      oacc[1][d4] = MFMA16(pa[1][0], vf0, oacc[1][d4]);
      oacc[1][d4] = MFMA16(pa[1][1], vf1, oacc[1][d4]);
    }
  }

#pragma unroll
  for (int qh = 0; qh < 2; ++qh) {
    float lb[4];
#pragma unroll
    for (int r = 0; r < 4; ++r) lb[r] = __shfl(l[qh], (lane & 48) | (lg * 4 + r));
#pragma unroll
    for (int r = 0; r < 4; ++r) {
      float inv = 1.f / lb[r];
      int q = q0w + qh * 16 + lg * 4 + r;
      u16* orow = Ao + ((size_t)(b * 2048 + q)) * 1024 + h * 64 + lr;
#pragma unroll
      for (int d4 = 0; d4 < 4; ++d4) orow[d4 * 16] = f2b(oacc[qh][d4][r] * inv);
    }
  }
}

// ---------------- output projection (f32 out), XCD-chunked ----------------
__global__ __launch_bounds__(256) void gemm_wo_k(const u16* __restrict__ Ab,
                                                 const u16* __restrict__ Wo,
                                                 float* __restrict__ Out) {
  __shared__ u16 As[128 * 32];
  __shared__ u16 Bs[128 * 32];
  const int wgid = blockIdx.x;
  const int xcd = wgid & 7;
  const int idx = wgid >> 3;             // 0..63
  const int mt = xcd * 8 + (idx >> 3);   // 0..63
  const int nt = idx & 7;
  const int tid = threadIdx.x, wave = tid >> 6, lane = tid & 63;
  const int wr = (wave >> 1) * 64, wc = (wave & 1) * 64;
  const int lr = lane & 15, lg = lane >> 4;
  const size_t arow = (size_t)(mt * 128 + wave * 32 + (lane >> 2)) * 1024 + (lane & 3) * 8;
  const size_t brow = (size_t)(nt * 128 + wave * 32 + (lane >> 2)) * 1024 + (lane & 3) * 8;
  u16* Ad0 = &As[(wave * 32) * 32];
  u16* Ad1 = &As[(wave * 32 + 16) * 32];
  u16* Bd0 = &Bs[(wave * 32) * 32];
  u16* Bd1 = &Bs[(wave * 32 + 16) * 32];

  f32x4 acc[4][4];
#pragma unroll
  for (int i = 0; i < 4; ++i)
#pragma unroll
    for (int j = 0; j < 4; ++j) acc[i][j] = (f32x4){0.f, 0.f, 0.f, 0.f};

  for (int kt = 0; kt < 1024; kt += 32) {
    glds16(Ab + arow + kt, Ad0);
    glds16(Ab + arow + kt + 16 * 1024, Ad1);
    glds16(Wo + brow + kt, Bd0);
    glds16(Wo + brow + kt + 16 * 1024, Bd1);
    __syncthreads();
    bf16x8 af[4], bfr[4];
#pragma unroll
    for (int mi = 0; mi < 4; ++mi)
      af[mi] = *(const bf16x8*)&As[(wr + mi * 16 + lr) * 32 + lg * 8];
#pragma unroll
    for (int ni = 0; ni < 4; ++ni)
      bfr[ni] = *(const bf16x8*)&Bs[(wc + ni * 16 + lr) * 32 + lg * 8];
#pragma unroll
    for (int mi = 0; mi < 4; ++mi)
#pragma unroll
      for (int ni = 0; ni < 4; ++ni)
        acc[mi][ni] = MFMA16(af[mi], bfr[ni], acc[mi][ni]);
    __syncthreads();
  }
#pragma unroll
  for (int mi = 0; mi < 4; ++mi)
#pragma unroll
    for (int ni = 0; ni < 4; ++ni) {
      int row0 = mt * 128 + wr + mi * 16 + lg * 4;
      int col = nt * 128 + wc + ni * 16 + lr;
#pragma unroll
      for (int r = 0; r < 4; ++r)
        Out[(size_t)(row0 + r) * 1024 + col] = acc[mi][ni][r];
    }
}

extern "C" void kernel_launch(void* const* d_in, const int* in_sizes, int n_in,
                              void* d_out, int out_size, void* d_ws, size_t ws_size,
                              hipStream_t stream) {
  const float* x = (const float*)d_in[0];
  const int* pos = (const int*)d_in[1];
  const float* wq = (const float*)d_in[2];
  const float* wk = (const float*)d_in[3];
  const float* wv = (const float*)d_in[4];
  const float* wo = (const float*)d_in[5];

  char* ws = (char*)d_ws;
  u16* xb = (u16*)ws;
  u16* wqb = xb + 8388608;
  u16* wkb = wqb + 1048576;
  u16* wvb = wkb + 1048576;
  u16* wob = wvb + 1048576;
  float2* tab = (float2*)(ws + 25165824);
  u16* Qp = (u16*)(ws + 27262976);
  u16* Kp = (u16*)(ws + 27262976 + 16777216);
  u16* Vt = (u16*)(ws + 27262976 + 2 * 16777216);
  u16* Ao = (u16*)(ws + 27262976 + 3 * 16777216);

  hipLaunchKernelGGL(cvt_k, dim3(12288), dim3(256), 0, stream, x, wq, wk, wv, wo, xb);
  hipLaunchKernelGGL(rope_tab_k, dim3(1024), dim3(256), 0, stream, pos, tab);
  hipLaunchKernelGGL(gemm_qkv_k, dim3(1536), dim3(256), 0, stream, xb, wqb, wkb, wvb,
                     tab, Qp, Kp, Vt);
  hipLaunchKernelGGL(fattn_k, dim3(1024), dim3(256), 0, stream, Qp, Kp, Vt, Ao);
  hipLaunchKernelGGL(gemm_wo_k, dim3(512), dim3(256), 0, stream, Ao, wob, (float*)d_out);
}